// Round 15
// baseline (391.080 us; speedup 1.0000x reference)
//
#include <hip/hip_runtime.h>
#include <hip/hip_bf16.h>

#define BATCH 16
#define CINC 96
#define HGT 112
#define WID 112
#define HW 12544          // 112*112
#define C1N 192
#define C2N 384
#define EPSV 1e-5f

typedef _Float16 f16x8 __attribute__((ext_vector_type(8)));
typedef _Float16 f16x4 __attribute__((ext_vector_type(4)));
typedef float    f32x4 __attribute__((ext_vector_type(4)));

// d_ws layout (float offsets unless noted)
#define WS_S      0        // 16*96 f32 h-sums (zeroed each launch)
#define WS_A1B1   1536     // 16*192 f32
#define WS_W1F    4608     // 192*3
#define WS_B1F    5184     // 192
#define WS_W2F    5376     // 384*3
#define WS_B2F    6528     // 384
#define WS_S3     6912     // 96
#define WS_B3     7008     // 96
#define WS_WPF_BYTES (7104*4)                    // f16 wpf[ksg][rt][lane][8]
#define WS_H_BYTES   (WS_WPF_BYTES + CINC*C2N*2) // f16 h[16][96][12544] = 38.5 MB

// ---------------- prep: fold BN into weights; Wp -> kstep-contiguous fragments --
// wpf[((ksg*6+rt)*64+lane)*8+e] = Wp[rt*16+(lane&15)][ksg*32+(lane>>4)*8+e]
// Wp[m][k] = w_pw[m][(k%64)*6 + k/64]  (channel shuffle groups=6 folded)
__global__ void k_prep(const float* __restrict__ wdw1, const float* __restrict__ g1,
                       const float* __restrict__ bb1, const float* __restrict__ m1,
                       const float* __restrict__ v1,
                       const float* __restrict__ wdw2, const float* __restrict__ g2,
                       const float* __restrict__ bb2, const float* __restrict__ m2,
                       const float* __restrict__ v2,
                       const float* __restrict__ wpw, const float* __restrict__ g3,
                       const float* __restrict__ bb3, const float* __restrict__ m3,
                       const float* __restrict__ v3,
                       float* ws)
{
    int t = blockIdx.x * blockDim.x + threadIdx.x;
    int stride = gridDim.x * blockDim.x;
    float* w1f = ws + WS_W1F; float* b1f = ws + WS_B1F;
    float* w2f = ws + WS_W2F; float* b2f = ws + WS_B2F;
    float* s3  = ws + WS_S3;  float* b3f = ws + WS_B3;
    _Float16* wpf = (_Float16*)((char*)ws + WS_WPF_BYTES);

    for (int c = t; c < C1N; c += stride) {
        float s = g1[c] / sqrtf(v1[c] + EPSV);
        w1f[c*3+0] = wdw1[c*3+0] * s;
        w1f[c*3+1] = wdw1[c*3+1] * s;
        w1f[c*3+2] = wdw1[c*3+2] * s;
        b1f[c] = bb1[c] - m1[c] * s;
    }
    for (int c = t; c < C2N; c += stride) {
        float s = g2[c] / sqrtf(v2[c] + EPSV);
        w2f[c*3+0] = wdw2[c*3+0] * s;
        w2f[c*3+1] = wdw2[c*3+1] * s;
        w2f[c*3+2] = wdw2[c*3+2] * s;
        b2f[c] = bb2[c] - m2[c] * s;
    }
    for (int c = t; c < CINC; c += stride) {
        float s = g3[c] / sqrtf(v3[c] + EPSV);
        s3[c] = s; b3f[c] = bb3[c] - m3[c] * s;
    }
    for (int idx = t; idx < CINC * C2N; idx += stride) {
        int e = idx & 7;
        int l2 = idx >> 3;
        int lane = l2 & 63;
        int l3 = l2 >> 6;
        int rt = l3 % 6, ksg = l3 / 6;
        int m = rt * 16 + (lane & 15);
        int k = ksg * 32 + (lane >> 4) * 8 + e;
        int o = (k & 63) * 6 + (k >> 6);
        wpf[idx] = (_Float16)wpw[m * C2N + o];
    }
}

// x-data for one channel pair
struct PairX {
    f32x4 T[2], M[2], B[2];
    float eT[2], eM[2], eB[2];
};

// ---------------- main: 6 x (pipelined dw(64k) -> 2-kstep MFMA) -> h+sums ------
// block = 4 rows x 64 cols; LDS 49.5 KB -> 3 blocks/CU
__global__ __launch_bounds__(256, 3) void k_main9(const float* __restrict__ x,
                                                  const float* __restrict__ ws,
                                                  float* __restrict__ sums,
                                                  _Float16* __restrict__ h_out)
{
    __shared__ __align__(16) char smem[49152];   // u: [0,36864) pos*144; wpf: [36864,49152)
    __shared__ float ssum[CINC];

    int t   = threadIdx.x;
    int bid = blockIdx.x;
    int logical = (bid & 7) * 112 + (bid >> 3);   // XCD-chunked (896 = 8*112)
    int b   = logical / 56;
    int rem = logical - b * 56;
    int y0  = (rem >> 1) * 4;
    int x0  = (rem & 1) * 48;

    int wv = t >> 6, lane = t & 63;
    int r = lane >> 4, c4 = lane & 15;
    int gy = y0 + r;
    int gc = x0 + 4 * c4;
    int col16 = c4, g = r;                        // MFMA-phase aliases

    const float* w1f = ws + WS_W1F; const float* b1f = ws + WS_B1F;
    const float* w2f = ws + WS_W2F; const float* b2f = ws + WS_B2F;

    if (t < CINC) ssum[t] = 0.f;

    bool ymok = gy >= 1;
    bool ypok = gy + 1 < HGT;
    bool isE  = (c4 == 0) | (c4 == 15);
    int  ecol = (c4 == 0) ? (x0 - 1) : (x0 + 64);
    bool ev   = isE && ((unsigned)ecol < (unsigned)WID);
    int  secol = ev ? ecol : 0;
    int  tm = ymok ? -WID : 0;
    int  tp = ypok ?  WID : 0;

    f32x4 acc[6][4];
    #pragma unroll
    for (int rt = 0; rt < 6; ++rt)
        #pragma unroll
        for (int ct = 0; ct < 4; ++ct) acc[rt][ct] = (f32x4){0.f, 0.f, 0.f, 0.f};

    f16x8* wpf_s = (f16x8*)(smem + 36864);
    const f16x8* wpf_g = (const f16x8*)((const char*)ws + WS_WPF_BYTES);
    long xb = (long)b * CINC * HW;
    const float* xw = x + xb + (long)gy * WID;    // + cu*HW + col

    int rotbase = 3 * r + c4;
    char* ub0 = smem + (r * 64 + 4 * c4) * 144;

    // prefetch chunk 0's Wp fragments (768 f16x8 = 3/thread)
    f16x8 nw0 = wpf_g[t];
    f16x8 nw1 = wpf_g[256 + t];
    f16x8 nw2 = wpf_g[512 + t];

    #define LOADCH(dst, q, cuq) {                                         \
        const float* p_ = xw + (long)(cuq) * HW;                          \
        (dst).M[q] = *(const f32x4*)(p_ + gc);                            \
        (dst).T[q] = *(const f32x4*)(p_ + gc + tm);                       \
        (dst).B[q] = *(const f32x4*)(p_ + gc + tp);                       \
        if (isE) {                                                        \
            const float* e_ = p_ + secol;                                 \
            (dst).eM[q] = e_[0]; (dst).eT[q] = e_[tm]; (dst).eB[q] = e_[tp]; \
        } }

    PairX A, B;
    LOADCH(A, 0, wv * 4 + 0)
    LOADCH(A, 1, wv * 4 + 1)

    for (int chunk = 0; chunk < 6; ++chunk) {
        if (chunk) __syncthreads();       // prev MFMA reads done before overwrite

        // stage Wp fragments from prefetch regs (pure ds_write)
        wpf_s[t] = nw0;
        wpf_s[256 + t] = nw1;
        wpf_s[512 + t] = nw2;

        int cbase = chunk * 16 + wv * 4;

        // 2 pairs, software-pipelined
        #pragma unroll
        for (int p = 0; p < 2; ++p) {
            if (p == 0) { LOADCH(B, 0, cbase + 2) LOADCH(B, 1, cbase + 3) }
            else if (chunk < 5) {        // prefetch next chunk's pair 0 (A is free)
                LOADCH(A, 0, cbase + 16)
                LOADCH(A, 1, cbase + 17)
            }
            PairX& C = (p == 1) ? B : A;

            f16x4 uv[2][4];
            #pragma unroll
            for (int q = 0; q < 2; ++q) {
                int cu = cbase + 2 * p + q;
                int c1a = cu * 2;
                float wa0 = w1f[c1a*3+0], wa1 = w1f[c1a*3+1], wa2 = w1f[c1a*3+2], ba = b1f[c1a];
                float wb0 = w1f[c1a*3+3], wb1 = w1f[c1a*3+4], wb2 = w1f[c1a*3+5], bb = b1f[c1a+1];

                float va[4], vb[4];
                #pragma unroll
                for (int j = 0; j < 4; ++j) {
                    float tt = ymok ? C.T[q][j] : 0.f;
                    float bt = ypok ? C.B[q][j] : 0.f;
                    va[j] = fmaf(wa0, tt, fmaf(wa1, C.M[q][j], fmaf(wa2, bt, ba)));
                    vb[j] = fmaf(wb0, tt, fmaf(wb1, C.M[q][j], fmaf(wb2, bt, bb)));
                }
                // conv2 zero-pads BN1 output: out-of-image edge column -> 0
                float etS = (ymok && ev) ? C.eT[q] : 0.f;
                float ebS = (ypok && ev) ? C.eB[q] : 0.f;
                float emS = ev ? C.eM[q] : 0.f;
                float vea = ev ? fmaf(wa0, etS, fmaf(wa1, emS, fmaf(wa2, ebS, ba))) : 0.f;
                float veb = ev ? fmaf(wb0, etS, fmaf(wb1, emS, fmaf(wb2, ebS, bb))) : 0.f;

                float vLa = __shfl(va[3], (lane + 63) & 63);
                float vLb = __shfl(vb[3], (lane + 63) & 63);
                float vRa = __shfl(va[0], (lane + 1) & 63);
                float vRb = __shfl(vb[0], (lane + 1) & 63);
                if (c4 == 0)  { vLa = vea; vLb = veb; }
                if (c4 == 15) { vRa = vea; vRb = veb; }

                int c2b = cu * 4;
                float pa[6] = {vLa, va[0], va[1], va[2], va[3], vRa};
                float pb[6] = {vLb, vb[0], vb[1], vb[2], vb[3], vRb};
                #pragma unroll
                for (int j = 0; j < 4; ++j) {
                    #pragma unroll
                    for (int jj = 0; jj < 4; ++jj) {
                        float p0 = (jj < 2) ? pa[j]     : pb[j];
                        float p1 = (jj < 2) ? pa[j + 1] : pb[j + 1];
                        float p2 = (jj < 2) ? pa[j + 2] : pb[j + 2];
                        float tv = fmaf(w2f[(c2b+jj)*3+0], p0,
                                   fmaf(w2f[(c2b+jj)*3+1], p1,
                                   fmaf(w2f[(c2b+jj)*3+2], p2, b2f[c2b+jj])));
                        uv[q][j][jj] = (_Float16)fminf(fmaxf(tv, 0.f), 6.f);
                    }
                }
            }
            // paired 16-B store: cell = wv*2+p (of 8), rotated into 9 slots
            int slot = (wv * 2 + p + rotbase) % 9;
            char* ubase = ub0 + slot * 16;
            #pragma unroll
            for (int j = 0; j < 4; ++j) {
                f16x8 w = __builtin_shufflevector(uv[0][j], uv[1][j], 0, 1, 2, 3, 4, 5, 6, 7);
                *(f16x8*)(ubase + j * 144) = w;
            }
        }

        // prefetch next chunk's Wp during barrier + MFMA
        if (chunk < 5) {
            int cb = (chunk + 1) * 768;
            nw0 = wpf_g[cb + t];
            nw1 = wpf_g[cb + 256 + t];
            nw2 = wpf_g[cb + 512 + t];
        }
        __syncthreads();   // u + wpf_s ready

        // MFMA: 2 k-steps
        #pragma unroll
        for (int ks = 0; ks < 2; ++ks) {
            f16x8 bfr[4];
            #pragma unroll
            for (int ct = 0; ct < 4; ++ct) {
                int pos = wv * 64 + ct * 16 + col16;
                int rb = 3 * (pos >> 6) + ((pos & 63) >> 2);
                int sl = (ks * 4 + g + rb) % 9;
                bfr[ct] = *(const f16x8*)(smem + pos * 144 + sl * 16);
            }
            #pragma unroll
            for (int rt = 0; rt < 6; ++rt) {
                f16x8 afr = wpf_s[(ks * 6 + rt) * 64 + lane];
                #pragma unroll
                for (int ct = 0; ct < 4; ++ct)
                    acc[rt][ct] = __builtin_amdgcn_mfma_f32_16x16x32_f16(afr, bfr[ct], acc[rt][ct], 0, 0, 0);
            }
        }
    }
    __syncthreads();   // last MFMA reads done before aliasing smem with h

    // ---- epilogue: bn3 -> h (f16) in two 48-channel LDS passes -> stores+sums --
    _Float16* h_s = (_Float16*)smem;   // [48][264]
    const float* s3  = ws + WS_S3;
    const float* b3f = ws + WS_B3;
    #pragma unroll
    for (int pass = 0; pass < 2; ++pass) {
        #pragma unroll
        for (int rt3 = 0; rt3 < 3; ++rt3) {
            int rt = pass * 3 + rt3;
            #pragma unroll
            for (int ct = 0; ct < 4; ++ct) {
                int p = wv * 64 + ct * 16 + col16;
                #pragma unroll
                for (int rr = 0; rr < 4; ++rr) {
                    int m = rt * 16 + g * 4 + rr;
                    h_s[(rt3 * 16 + g * 4 + rr) * 264 + p] =
                        (_Float16)fmaf(acc[rt][ct][rr], s3[m], b3f[m]);
                }
            }
        }
        __syncthreads();
        #pragma unroll
        for (int i = 0; i < 6; ++i) {
            int flat = i * 2048 + t * 8;        // covers 48*256
            int mL = flat >> 8;
            int p = flat & 255;
            f16x8 hv = *(const f16x8*)(h_s + mL * 264 + p);
            int m = pass * 48 + mL;
            int row = y0 + (p >> 6);
            int colg = x0 + (p & 63);
            *(f16x8*)(h_out + ((long)(b * CINC + m)) * HW + (long)row * WID + colg) = hv;

            float s = 0.f;
            if (!(x0 == 48 && (p & 63) < 16)) {  // overlap cols 48..63 counted by half-0
                #pragma unroll
                for (int e = 0; e < 8; ++e) s += (float)hv[e];
            }
            s += __shfl_xor(s, 1);
            s += __shfl_xor(s, 2);
            s += __shfl_xor(s, 4);
            s += __shfl_xor(s, 8);
            s += __shfl_xor(s, 16);
            if ((lane & 31) == 0) atomicAdd(&ssum[m], s);
        }
        __syncthreads();
    }
    if (t < CINC) atomicAdd(&sums[b * CINC + t], ssum[t]);
}

// ---------------- gates: mean(h) -> fc1+relu -> fc2 -> hardsig -> a1,b1 -------
__global__ __launch_bounds__(192) void k_gates(const float* __restrict__ sums,
                                               const float* __restrict__ fc1w,
                                               const float* __restrict__ fc1b,
                                               const float* __restrict__ fc2w,
                                               const float* __restrict__ fc2b,
                                               float* __restrict__ a1b1)
{
    __shared__ float mean_s[CINC];
    __shared__ float mid[24];
    int b = blockIdx.x;
    int t = threadIdx.x;     // 192

    if (t < CINC) mean_s[t] = sums[b * CINC + t] * (1.0f / 12544.0f);
    __syncthreads();
    if (t < 24) {
        float d = fc1b[t];
        #pragma unroll 4
        for (int c = 0; c < CINC; ++c) d = fmaf(fc1w[t * CINC + c], mean_s[c], d);
        mid[t] = fmaxf(d, 0.f);
    }
    __syncthreads();
    {
        float d = fc2b[t];
        #pragma unroll
        for (int j = 0; j < 24; ++j) d = fmaf(fc2w[t * 24 + j], mid[j], d);
        float y = fminf(fmaxf(d + 3.f, 0.f), 6.f) * (1.f / 6.f);
        y = (y - 0.5f) * 4.f;
        a1b1[b * 192 + t] = (t < CINC) ? (y + 1.f) : y;
    }
}

// ---------------- final: h*a1 + roll(h)*b1, shuffle(48), + x (pure streaming) --
__global__ __launch_bounds__(256) void k_final(const _Float16* __restrict__ h,
                                               const float* __restrict__ xin,
                                               const float* __restrict__ a1b1,
                                               float* __restrict__ out)
{
    int q = blockIdx.x * 256 + threadIdx.x;      // 4,816,896 quads total (exact)
    int pos4 = q % 3136;
    int bo = q / 3136;
    int o = bo % CINC, b = bo / CINC;
    int c = (o % 48) * 2 + (o / 48);             // shuffle(48) folded
    int cn = (c + 1) % CINC;                      // channel roll

    float av = a1b1[b * 192 + c];
    float bv = a1b1[b * 192 + 96 + c];

    long hb = (long)b * CINC * HW;
    f16x4 hv4 = *(const f16x4*)(h + hb + (long)c  * HW + pos4 * 4);
    f16x4 h2v = *(const f16x4*)(h + hb + (long)cn * HW + pos4 * 4);

    long xo = ((long)(b * CINC + o)) * HW + pos4 * 4;
    f32x4 xv = *(const f32x4*)(xin + xo);
    f32x4 rr;
    #pragma unroll
    for (int j = 0; j < 4; ++j)
        rr[j] = fmaf((float)hv4[j], av, fmaf((float)h2v[j], bv, xv[j]));
    *(f32x4*)(out + xo) = rr;
}

extern "C" void kernel_launch(void* const* d_in, const int* in_sizes, int n_in,
                              void* d_out, int out_size, void* d_ws, size_t ws_size,
                              hipStream_t stream)
{
    const float* x    = (const float*)d_in[0];
    const float* wdw1 = (const float*)d_in[1];
    const float* g1   = (const float*)d_in[2];
    const float* b1   = (const float*)d_in[3];
    const float* m1   = (const float*)d_in[4];
    const float* v1   = (const float*)d_in[5];
    const float* wdw2 = (const float*)d_in[6];
    const float* g2   = (const float*)d_in[7];
    const float* b2   = (const float*)d_in[8];
    const float* m2   = (const float*)d_in[9];
    const float* v2   = (const float*)d_in[10];
    const float* wpw  = (const float*)d_in[11];
    const float* g3   = (const float*)d_in[12];
    const float* b3   = (const float*)d_in[13];
    const float* m3   = (const float*)d_in[14];
    const float* v3   = (const float*)d_in[15];
    const float* fc1w = (const float*)d_in[16];
    const float* fc1b = (const float*)d_in[17];
    const float* fc2w = (const float*)d_in[18];
    const float* fc2b = (const float*)d_in[19];

    float* ws   = (float*)d_ws;
    float* sums = ws + WS_S;
    float* a1b1 = ws + WS_A1B1;
    _Float16* hbuf = (_Float16*)((char*)d_ws + WS_H_BYTES);
    float* out  = (float*)d_out;

    hipMemsetAsync(sums, 0, 1536 * sizeof(float), stream);
    k_prep<<<dim3(40), dim3(256), 0, stream>>>(
        wdw1, g1, b1, m1, v1, wdw2, g2, b2, m2, v2,
        wpw, g3, b3, m3, v3, ws);
    k_main9<<<dim3(896), dim3(256), 0, stream>>>(x, ws, sums, hbuf);
    k_gates<<<dim3(BATCH), dim3(192), 0, stream>>>(sums, fc1w, fc1b, fc2w, fc2b, a1b1);
    k_final<<<dim3(4816896 / 256), dim3(256), 0, stream>>>(hbuf, x, a1b1, out);
}

// Round 17
// 197.618 us; speedup vs baseline: 1.9790x; 1.9790x over previous
//
#include <hip/hip_runtime.h>
#include <hip/hip_bf16.h>

#define BATCH 16
#define CINC 96
#define HGT 112
#define WID 112
#define HW 12544          // 112*112
#define C1N 192
#define C2N 384
#define EPSV 1e-5f

typedef _Float16 f16x8 __attribute__((ext_vector_type(8)));
typedef _Float16 f16x4 __attribute__((ext_vector_type(4)));
typedef float    f32x4 __attribute__((ext_vector_type(4)));

// d_ws layout (float offsets unless noted)
#define WS_S      0        // 16*96 f32 h-sums (zeroed each launch)
#define WS_A1B1   1536     // 16*192 f32
#define WS_W1F    4608     // 192*3
#define WS_B1F    5184     // 192
#define WS_W2F    5376     // 384*3
#define WS_B2F    6528     // 384
#define WS_S3     6912     // 96
#define WS_B3     7008     // 96
#define WS_WPF_BYTES (7104*4)                    // f16 wpf[ksg][rt][lane][8]
#define WS_H_BYTES   (WS_WPF_BYTES + CINC*C2N*2) // f16 h[16][96][12544] = 38.5 MB

// ---------------- prep: fold BN into weights; Wp -> kstep-contiguous fragments --
// wpf[((ksg*6+rt)*64+lane)*8+e] = Wp[rt*16+(lane&15)][ksg*32+(lane>>4)*8+e]
// Wp[m][k] = w_pw[m][(k%64)*6 + k/64]  (channel shuffle groups=6 folded)
__global__ void k_prep(const float* __restrict__ wdw1, const float* __restrict__ g1,
                       const float* __restrict__ bb1, const float* __restrict__ m1,
                       const float* __restrict__ v1,
                       const float* __restrict__ wdw2, const float* __restrict__ g2,
                       const float* __restrict__ bb2, const float* __restrict__ m2,
                       const float* __restrict__ v2,
                       const float* __restrict__ wpw, const float* __restrict__ g3,
                       const float* __restrict__ bb3, const float* __restrict__ m3,
                       const float* __restrict__ v3,
                       float* ws)
{
    int t = blockIdx.x * blockDim.x + threadIdx.x;
    int stride = gridDim.x * blockDim.x;
    float* w1f = ws + WS_W1F; float* b1f = ws + WS_B1F;
    float* w2f = ws + WS_W2F; float* b2f = ws + WS_B2F;
    float* s3  = ws + WS_S3;  float* b3f = ws + WS_B3;
    _Float16* wpf = (_Float16*)((char*)ws + WS_WPF_BYTES);

    for (int c = t; c < C1N; c += stride) {
        float s = g1[c] / sqrtf(v1[c] + EPSV);
        w1f[c*3+0] = wdw1[c*3+0] * s;
        w1f[c*3+1] = wdw1[c*3+1] * s;
        w1f[c*3+2] = wdw1[c*3+2] * s;
        b1f[c] = bb1[c] - m1[c] * s;
    }
    for (int c = t; c < C2N; c += stride) {
        float s = g2[c] / sqrtf(v2[c] + EPSV);
        w2f[c*3+0] = wdw2[c*3+0] * s;
        w2f[c*3+1] = wdw2[c*3+1] * s;
        w2f[c*3+2] = wdw2[c*3+2] * s;
        b2f[c] = bb2[c] - m2[c] * s;
    }
    for (int c = t; c < CINC; c += stride) {
        float s = g3[c] / sqrtf(v3[c] + EPSV);
        s3[c] = s; b3f[c] = bb3[c] - m3[c] * s;
    }
    for (int idx = t; idx < CINC * C2N; idx += stride) {
        int e = idx & 7;
        int l2 = idx >> 3;
        int lane = l2 & 63;
        int l3 = l2 >> 6;
        int rt = l3 % 6, ksg = l3 / 6;
        int m = rt * 16 + (lane & 15);
        int k = ksg * 32 + (lane >> 4) * 8 + e;
        int o = (k & 63) * 6 + (k >> 6);
        wpf[idx] = (_Float16)wpw[m * C2N + o];
    }
}

// x-data for one channel pair (edge scalars loaded lazily, not stored)
struct PairX { f32x4 T[2], M[2], B[2]; };

// ---------------- main: 2x64 tile, waves split M; 6 x (dw(64k) -> MFMA) --------
// acc[3][4]=48 regs -> fits 3 blocks/CU at __launch_bounds__(256,3)
__global__ __launch_bounds__(256, 3) void k_main10(const float* __restrict__ x,
                                                   const float* __restrict__ ws,
                                                   float* __restrict__ sums,
                                                   _Float16* __restrict__ h_out)
{
    __shared__ __align__(16) char smem[30720];   // u: [0,18432) pos*144; wpf: [18432,30720)
    __shared__ float ssum[CINC];

    int t   = threadIdx.x;
    int bid = blockIdx.x;
    int logical = (bid & 7) * 224 + (bid >> 3);   // XCD-chunked (1792 = 8*224)
    int b   = logical / 112;
    int rem = logical - b * 112;
    int y0  = (rem >> 1) * 2;                     // 56 row-pairs
    int x0  = (rem & 1) * 48;                     // 2 col-halves

    int wv = t >> 6, lane = t & 63;
    // gather role: row r (0..1), sub-channel half, col-quad c4
    int r   = (lane >> 4) & 1;
    int sub = lane >> 5;
    int c4  = lane & 15;
    int gy = y0 + r;
    int gc = x0 + 4 * c4;
    // MFMA role: wave = (m-half mh, row rw); lane = (g<<4)|col16
    int mh = wv & 1, rw = wv >> 1;
    int col16 = lane & 15, g = lane >> 4;

    const float* w1f = ws + WS_W1F; const float* b1f = ws + WS_B1F;
    const float* w2f = ws + WS_W2F; const float* b2f = ws + WS_B2F;

    if (t < CINC) ssum[t] = 0.f;

    bool ymok = gy >= 1;
    bool ypok = gy + 1 < HGT;
    bool isE  = (c4 == 0) | (c4 == 15);
    int  ecol = (c4 == 0) ? (x0 - 1) : (x0 + 64);
    bool ev   = isE && ((unsigned)ecol < (unsigned)WID);
    int  secol = ev ? ecol : 0;
    int  tm = ymok ? -WID : 0;
    int  tp = ypok ?  WID : 0;

    f32x4 acc[3][4];
    #pragma unroll
    for (int rt = 0; rt < 3; ++rt)
        #pragma unroll
        for (int ct = 0; ct < 4; ++ct) acc[rt][ct] = (f32x4){0.f, 0.f, 0.f, 0.f};

    f16x8* wpf_s = (f16x8*)(smem + 18432);
    const f16x8* wpf_g = (const f16x8*)((const char*)ws + WS_WPF_BYTES);
    long xb = (long)b * CINC * HW;
    const float* xw = x + xb + (long)gy * WID;    // + cu*HW + col

    int rotbase = 3 * r + c4;
    char* ub0 = smem + (r * 64 + 4 * c4) * 144;
    int kc = wv * 2 + sub;                        // k-cell 0..7 within chunk

    #define LOADCH(dst, q, cuq) {                               \
        const float* p_ = xw + (long)(cuq) * HW + gc;           \
        (dst).M[q] = *(const f32x4*)p_;                         \
        (dst).T[q] = *(const f32x4*)(p_ + tm);                  \
        (dst).B[q] = *(const f32x4*)(p_ + tp);                  }

    // prefetch chunk 0: x pair + Wp fragments (768 f16x8 = 3/thread)
    PairX cur, nxt;
    int cbase0 = wv * 4 + sub * 2;
    LOADCH(cur, 0, cbase0)
    LOADCH(cur, 1, cbase0 + 1)
    f16x8 nw0 = wpf_g[t];
    f16x8 nw1 = wpf_g[256 + t];
    f16x8 nw2 = wpf_g[512 + t];

    for (int chunk = 0; chunk < 6; ++chunk) {
        if (chunk) __syncthreads();       // prev MFMA reads done before overwrite

        // stage Wp fragments from prefetch regs (pure ds_write)
        wpf_s[t] = nw0;
        wpf_s[256 + t] = nw1;
        wpf_s[512 + t] = nw2;

        int cu0 = chunk * 16 + wv * 4 + sub * 2;

        // issue next chunk's x loads (hide under u-compute)
        if (chunk < 5) {
            LOADCH(nxt, 0, cu0 + 16)
            LOADCH(nxt, 1, cu0 + 17)
        }

        // compute u for the 2 channels of this thread's pair
        f16x4 uv[2][4];
        #pragma unroll
        for (int q = 0; q < 2; ++q) {
            int cu = cu0 + q;
            int c1a = cu * 2;
            float wa0 = w1f[c1a*3+0], wa1 = w1f[c1a*3+1], wa2 = w1f[c1a*3+2], ba = b1f[c1a];
            float wb0 = w1f[c1a*3+3], wb1 = w1f[c1a*3+4], wb2 = w1f[c1a*3+5], bb = b1f[c1a+1];

            float va[4], vb[4];
            #pragma unroll
            for (int j = 0; j < 4; ++j) {
                float tt = ymok ? cur.T[q][j] : 0.f;
                float bt = ypok ? cur.B[q][j] : 0.f;
                va[j] = fmaf(wa0, tt, fmaf(wa1, cur.M[q][j], fmaf(wa2, bt, ba)));
                vb[j] = fmaf(wb0, tt, fmaf(wb1, cur.M[q][j], fmaf(wb2, bt, bb)));
            }
            // edge column (lazy loads; conv2 zero-pads BN1 output outside image)
            float vea = 0.f, veb = 0.f;
            if (ev) {
                const float* e_ = xw + (long)cu * HW + secol;
                float eM = e_[0];
                float eT = ymok ? e_[tm] : 0.f;
                float eB = ypok ? e_[tp] : 0.f;
                vea = fmaf(wa0, eT, fmaf(wa1, eM, fmaf(wa2, eB, ba)));
                veb = fmaf(wb0, eT, fmaf(wb1, eM, fmaf(wb2, eB, bb)));
            }

            float vLa = __shfl(va[3], (lane + 63) & 63);
            float vLb = __shfl(vb[3], (lane + 63) & 63);
            float vRa = __shfl(va[0], (lane + 1) & 63);
            float vRb = __shfl(vb[0], (lane + 1) & 63);
            if (c4 == 0)  { vLa = vea; vLb = veb; }
            if (c4 == 15) { vRa = vea; vRb = veb; }

            int c2b = cu * 4;
            float pa[6] = {vLa, va[0], va[1], va[2], va[3], vRa};
            float pb[6] = {vLb, vb[0], vb[1], vb[2], vb[3], vRb};
            #pragma unroll
            for (int j = 0; j < 4; ++j) {
                #pragma unroll
                for (int jj = 0; jj < 4; ++jj) {
                    float p0 = (jj < 2) ? pa[j]     : pb[j];
                    float p1 = (jj < 2) ? pa[j + 1] : pb[j + 1];
                    float p2 = (jj < 2) ? pa[j + 2] : pb[j + 2];
                    float tv = fmaf(w2f[(c2b+jj)*3+0], p0,
                               fmaf(w2f[(c2b+jj)*3+1], p1,
                               fmaf(w2f[(c2b+jj)*3+2], p2, b2f[c2b+jj])));
                    uv[q][j][jj] = (_Float16)fminf(fmaxf(tv, 0.f), 6.f);
                }
            }
        }
        // paired 16-B store into rotated slot (9 slots x 16B per 144-B row)
        {
            int slot = (kc + rotbase) % 9;
            char* ubase = ub0 + slot * 16;
            #pragma unroll
            for (int j = 0; j < 4; ++j) {
                f16x8 w = __builtin_shufflevector(uv[0][j], uv[1][j], 0, 1, 2, 3, 4, 5, 6, 7);
                *(f16x8*)(ubase + j * 144) = w;
            }
        }
        cur = nxt;

        // prefetch next chunk's Wp during barrier + MFMA
        if (chunk < 5) {
            int cb = (chunk + 1) * 768;
            nw0 = wpf_g[cb + t];
            nw1 = wpf_g[cb + 256 + t];
            nw2 = wpf_g[cb + 512 + t];
        }
        __syncthreads();   // u + wpf_s ready

        // MFMA: 2 k-steps; wave computes its 48-channel half over row rw
        #pragma unroll
        for (int ks = 0; ks < 2; ++ks) {
            f16x8 bfr[4];
            #pragma unroll
            for (int ct = 0; ct < 4; ++ct) {
                int pos = rw * 64 + ct * 16 + col16;
                int rot = 3 * rw + ct * 4 + (col16 >> 2);
                int sl = (ks * 4 + g + rot) % 9;
                bfr[ct] = *(const f16x8*)(smem + pos * 144 + sl * 16);
            }
            #pragma unroll
            for (int rt = 0; rt < 3; ++rt) {
                f16x8 afr = wpf_s[(ks * 6 + mh * 3 + rt) * 64 + lane];
                #pragma unroll
                for (int ct = 0; ct < 4; ++ct)
                    acc[rt][ct] = __builtin_amdgcn_mfma_f32_16x16x32_f16(afr, bfr[ct], acc[rt][ct], 0, 0, 0);
            }
        }
    }
    __syncthreads();   // last MFMA reads done before aliasing smem with h

    // ---- epilogue: bn3 -> h_s[96][136] (f16) -> coalesced stores + sums -------
    _Float16* h_s = (_Float16*)smem;   // 96*136*2 = 26112 B <= 30720
    const float* s3  = ws + WS_S3;
    const float* b3f = ws + WS_B3;
    #pragma unroll
    for (int rt = 0; rt < 3; ++rt) {
        #pragma unroll
        for (int ct = 0; ct < 4; ++ct) {
            int p = rw * 64 + ct * 16 + col16;
            #pragma unroll
            for (int rr = 0; rr < 4; ++rr) {
                int m = (mh * 3 + rt) * 16 + g * 4 + rr;
                h_s[m * 136 + p] = (_Float16)fmaf(acc[rt][ct][rr], s3[m], b3f[m]);
            }
        }
    }
    __syncthreads();

    #pragma unroll
    for (int i = 0; i < 6; ++i) {
        int flat = i * 2048 + t * 8;          // covers 96*128 exactly
        int m = flat >> 7;
        int p = flat & 127;
        f16x8 hv = *(const f16x8*)(h_s + m * 136 + p);
        int row = y0 + (p >> 6);
        int colg = x0 + (p & 63);
        *(f16x8*)(h_out + ((long)(b * CINC + m)) * HW + (long)row * WID + colg) = hv;

        float s = 0.f;
        if (!(x0 == 48 && (p & 63) < 16)) {   // overlap cols 48..63 counted by half-0
            #pragma unroll
            for (int e = 0; e < 8; ++e) s += (float)hv[e];
        }
        // 16 lanes per channel (128 pos / 8 per lane) -> 16-lane reduce ONLY
        s += __shfl_xor(s, 1);
        s += __shfl_xor(s, 2);
        s += __shfl_xor(s, 4);
        s += __shfl_xor(s, 8);
        if ((lane & 15) == 0) atomicAdd(&ssum[m], s);
    }
    __syncthreads();
    if (t < CINC) atomicAdd(&sums[b * CINC + t], ssum[t]);
}

// ---------------- gates: mean(h) -> fc1+relu -> fc2 -> hardsig -> a1,b1 -------
__global__ __launch_bounds__(192) void k_gates(const float* __restrict__ sums,
                                               const float* __restrict__ fc1w,
                                               const float* __restrict__ fc1b,
                                               const float* __restrict__ fc2w,
                                               const float* __restrict__ fc2b,
                                               float* __restrict__ a1b1)
{
    __shared__ float mean_s[CINC];
    __shared__ float mid[24];
    int b = blockIdx.x;
    int t = threadIdx.x;     // 192

    if (t < CINC) mean_s[t] = sums[b * CINC + t] * (1.0f / 12544.0f);
    __syncthreads();
    if (t < 24) {
        float d = fc1b[t];
        #pragma unroll 4
        for (int c = 0; c < CINC; ++c) d = fmaf(fc1w[t * CINC + c], mean_s[c], d);
        mid[t] = fmaxf(d, 0.f);
    }
    __syncthreads();
    {
        float d = fc2b[t];
        #pragma unroll
        for (int j = 0; j < 24; ++j) d = fmaf(fc2w[t * 24 + j], mid[j], d);
        float y = fminf(fmaxf(d + 3.f, 0.f), 6.f) * (1.f / 6.f);
        y = (y - 0.5f) * 4.f;
        a1b1[b * 192 + t] = (t < CINC) ? (y + 1.f) : y;
    }
}

// ---------------- final: h*a1 + roll(h)*b1, shuffle(48), + x (pure streaming) --
__global__ __launch_bounds__(256) void k_final(const _Float16* __restrict__ h,
                                               const float* __restrict__ xin,
                                               const float* __restrict__ a1b1,
                                               float* __restrict__ out)
{
    int q = blockIdx.x * 256 + threadIdx.x;      // 4,816,896 quads total (exact)
    int pos4 = q % 3136;
    int bo = q / 3136;
    int o = bo % CINC, b = bo / CINC;
    int c = (o % 48) * 2 + (o / 48);             // shuffle(48) folded
    int cn = (c + 1) % CINC;                      // channel roll

    float av = a1b1[b * 192 + c];
    float bv = a1b1[b * 192 + 96 + c];

    long hb = (long)b * CINC * HW;
    f16x4 hv4 = *(const f16x4*)(h + hb + (long)c  * HW + pos4 * 4);
    f16x4 h2v = *(const f16x4*)(h + hb + (long)cn * HW + pos4 * 4);

    long xo = ((long)(b * CINC + o)) * HW + pos4 * 4;
    f32x4 xv = *(const f32x4*)(xin + xo);
    f32x4 rr;
    #pragma unroll
    for (int j = 0; j < 4; ++j)
        rr[j] = fmaf((float)hv4[j], av, fmaf((float)h2v[j], bv, xv[j]));
    *(f32x4*)(out + xo) = rr;
}

extern "C" void kernel_launch(void* const* d_in, const int* in_sizes, int n_in,
                              void* d_out, int out_size, void* d_ws, size_t ws_size,
                              hipStream_t stream)
{
    const float* x    = (const float*)d_in[0];
    const float* wdw1 = (const float*)d_in[1];
    const float* g1   = (const float*)d_in[2];
    const float* b1   = (const float*)d_in[3];
    const float* m1   = (const float*)d_in[4];
    const float* v1   = (const float*)d_in[5];
    const float* wdw2 = (const float*)d_in[6];
    const float* g2   = (const float*)d_in[7];
    const float* b2   = (const float*)d_in[8];
    const float* m2   = (const float*)d_in[9];
    const float* v2   = (const float*)d_in[10];
    const float* wpw  = (const float*)d_in[11];
    const float* g3   = (const float*)d_in[12];
    const float* b3   = (const float*)d_in[13];
    const float* m3   = (const float*)d_in[14];
    const float* v3   = (const float*)d_in[15];
    const float* fc1w = (const float*)d_in[16];
    const float* fc1b = (const float*)d_in[17];
    const float* fc2w = (const float*)d_in[18];
    const float* fc2b = (const float*)d_in[19];

    float* ws   = (float*)d_ws;
    float* sums = ws + WS_S;
    float* a1b1 = ws + WS_A1B1;
    _Float16* hbuf = (_Float16*)((char*)d_ws + WS_H_BYTES);
    float* out  = (float*)d_out;

    hipMemsetAsync(sums, 0, 1536 * sizeof(float), stream);
    k_prep<<<dim3(40), dim3(256), 0, stream>>>(
        wdw1, g1, b1, m1, v1, wdw2, g2, b2, m2, v2,
        wpw, g3, b3, m3, v3, ws);
    k_main10<<<dim3(1792), dim3(256), 0, stream>>>(x, ws, sums, hbuf);
    k_gates<<<dim3(BATCH), dim3(192), 0, stream>>>(sums, fc1w, fc1b, fc2w, fc2b, a1b1);
    k_final<<<dim3(4816896 / 256), dim3(256), 0, stream>>>(hbuf, x, a1b1, out);
}

// Round 18
// 164.577 us; speedup vs baseline: 2.3763x; 1.2008x over previous
//
#include <hip/hip_runtime.h>
#include <hip/hip_bf16.h>

#define BATCH 16
#define CINC 96
#define HGT 112
#define WID 112
#define HW 12544          // 112*112
#define C1N 192
#define C2N 384
#define EPSV 1e-5f

typedef _Float16 f16x8 __attribute__((ext_vector_type(8)));
typedef _Float16 f16x4 __attribute__((ext_vector_type(4)));
typedef float    f32x4 __attribute__((ext_vector_type(4)));

// d_ws layout (float offsets unless noted)
#define WS_S      0        // 16*96 f32 h-sums (zeroed each launch)
#define WS_A1B1   1536     // 16*192 f32
#define WS_W1F    4608     // 192*3
#define WS_B1F    5184     // 192
#define WS_W2F    5376     // 384*3
#define WS_B2F    6528     // 384
#define WS_S3     6912     // 96
#define WS_B3     7008     // 96
#define WS_WPF_BYTES (7104*4)                    // f16 wpf[ksg][rt][lane][8]
#define WS_H_BYTES   (WS_WPF_BYTES + CINC*C2N*2) // f16 h[16][96][12544] = 38.5 MB

// ---------------- prep: fold BN into weights; Wp -> kstep-contiguous fragments --
// wpf[((ksg*6+rt)*64+lane)*8+e] = Wp[rt*16+(lane&15)][ksg*32+(lane>>4)*8+e]
// Wp[m][k] = w_pw[m][(k%64)*6 + k/64]  (channel shuffle groups=6 folded)
__global__ void k_prep(const float* __restrict__ wdw1, const float* __restrict__ g1,
                       const float* __restrict__ bb1, const float* __restrict__ m1,
                       const float* __restrict__ v1,
                       const float* __restrict__ wdw2, const float* __restrict__ g2,
                       const float* __restrict__ bb2, const float* __restrict__ m2,
                       const float* __restrict__ v2,
                       const float* __restrict__ wpw, const float* __restrict__ g3,
                       const float* __restrict__ bb3, const float* __restrict__ m3,
                       const float* __restrict__ v3,
                       float* ws)
{
    int t = blockIdx.x * blockDim.x + threadIdx.x;
    int stride = gridDim.x * blockDim.x;
    float* w1f = ws + WS_W1F; float* b1f = ws + WS_B1F;
    float* w2f = ws + WS_W2F; float* b2f = ws + WS_B2F;
    float* s3  = ws + WS_S3;  float* b3f = ws + WS_B3;
    _Float16* wpf = (_Float16*)((char*)ws + WS_WPF_BYTES);

    for (int c = t; c < C1N; c += stride) {
        float s = g1[c] / sqrtf(v1[c] + EPSV);
        w1f[c*3+0] = wdw1[c*3+0] * s;
        w1f[c*3+1] = wdw1[c*3+1] * s;
        w1f[c*3+2] = wdw1[c*3+2] * s;
        b1f[c] = bb1[c] - m1[c] * s;
    }
    for (int c = t; c < C2N; c += stride) {
        float s = g2[c] / sqrtf(v2[c] + EPSV);
        w2f[c*3+0] = wdw2[c*3+0] * s;
        w2f[c*3+1] = wdw2[c*3+1] * s;
        w2f[c*3+2] = wdw2[c*3+2] * s;
        b2f[c] = bb2[c] - m2[c] * s;
    }
    for (int c = t; c < CINC; c += stride) {
        float s = g3[c] / sqrtf(v3[c] + EPSV);
        s3[c] = s; b3f[c] = bb3[c] - m3[c] * s;
    }
    for (int idx = t; idx < CINC * C2N; idx += stride) {
        int e = idx & 7;
        int l2 = idx >> 3;
        int lane = l2 & 63;
        int l3 = l2 >> 6;
        int rt = l3 % 6, ksg = l3 / 6;
        int m = rt * 16 + (lane & 15);
        int k = ksg * 32 + (lane >> 4) * 8 + e;
        int o = (k & 63) * 6 + (k >> 6);
        wpf[idx] = (_Float16)wpw[m * C2N + o];
    }
}

// x-data for one channel pair (edge scalars loaded lazily)
struct PairX { f32x4 T[2], M[2], B[2]; };

// ---------------- main: dbuf BK=32 pipeline: MFMA(k-1) overlaps gather(k) ------
// block = 4 rows x 64 cols; u2[2]x20KB + wpf2[2]x6KB = 53.2 KB LDS
__global__ __launch_bounds__(256) void k_main11(const float* __restrict__ x,
                                                const float* __restrict__ ws,
                                                float* __restrict__ sums,
                                                _Float16* __restrict__ h_out)
{
    __shared__ __align__(16) char smem[53248];   // u2: [0,40960) pos*80; wpf2: [40960,53248)
    __shared__ float ssum[CINC];

    int t   = threadIdx.x;
    int bid = blockIdx.x;
    int logical = (bid & 7) * 112 + (bid >> 3);   // XCD-chunked (896 = 8*112)
    int b   = logical / 56;
    int rem = logical - b * 56;
    int y0  = (rem >> 1) * 4;
    int x0  = (rem & 1) * 48;

    int wv = t >> 6, lane = t & 63;
    int r = lane >> 4, c4 = lane & 15;            // gather role
    int gy = y0 + r;
    int gc = x0 + 4 * c4;
    int col16 = lane & 15, g = lane >> 4;         // MFMA role

    const float* w1f = ws + WS_W1F; const float* b1f = ws + WS_B1F;
    const float* w2f = ws + WS_W2F; const float* b2f = ws + WS_B2F;

    if (t < CINC) ssum[t] = 0.f;

    bool ymok = gy >= 1;
    bool ypok = gy + 1 < HGT;
    bool isE  = (c4 == 0) | (c4 == 15);
    int  ecol = (c4 == 0) ? (x0 - 1) : (x0 + 64);
    bool ev   = isE && ((unsigned)ecol < (unsigned)WID);
    int  secol = ev ? ecol : 0;
    int  tm = ymok ? -WID : 0;
    int  tp = ypok ?  WID : 0;

    f32x4 acc[6][4];
    #pragma unroll
    for (int rt = 0; rt < 6; ++rt)
        #pragma unroll
        for (int ct = 0; ct < 4; ++ct) acc[rt][ct] = (f32x4){0.f, 0.f, 0.f, 0.f};

    const f16x8* wpf_g = (const f16x8*)((const char*)ws + WS_WPF_BYTES);
    long xb = (long)b * CINC * HW;
    const float* xw = x + xb + (long)gy * WID;    // + cu*HW + col

    int rotbase = 3 * r + c4;
    int slot = (wv + rotbase) % 5;                // write slot (cell index = wv)

    #define LOADCH(dst, q, cuq) {                               \
        const float* p_ = xw + (long)(cuq) * HW + gc;           \
        (dst).M[q] = *(const f32x4*)p_;                         \
        (dst).T[q] = *(const f32x4*)(p_ + tm);                  \
        (dst).B[q] = *(const f32x4*)(p_ + tp);                  }

    // MFMA for chunk j (reads buffers j&1)
    #define DO_MFMA(j) {                                                          \
        int jb_ = (j) & 1;                                                        \
        const char* ub_ = smem + jb_ * 20480;                                     \
        const f16x8* wp_ = (const f16x8*)(smem + 40960 + jb_ * 6144);             \
        f16x8 bfr[4];                                                             \
        _Pragma("unroll")                                                         \
        for (int ct = 0; ct < 4; ++ct) {                                          \
            int pos = wv * 64 + ct * 16 + col16;                                  \
            int sl = (g + 3 * wv + ct * 4 + (col16 >> 2)) % 5;                    \
            bfr[ct] = *(const f16x8*)(ub_ + pos * 80 + sl * 16);                  \
        }                                                                         \
        _Pragma("unroll")                                                         \
        for (int rt = 0; rt < 6; ++rt) {                                          \
            f16x8 afr = wp_[rt * 64 + lane];                                      \
            _Pragma("unroll")                                                     \
            for (int ct = 0; ct < 4; ++ct)                                        \
                acc[rt][ct] = __builtin_amdgcn_mfma_f32_16x16x32_f16(afr, bfr[ct], acc[rt][ct], 0, 0, 0); \
        } }

    // prologue: prefetch chunk 0's Wp + x pair
    PairX cur, nxt;
    LOADCH(cur, 0, wv * 2)
    LOADCH(cur, 1, wv * 2 + 1)
    f16x8 nw0 = wpf_g[t];
    f16x8 nw1 = nw0;
    if (t < 128) nw1 = wpf_g[256 + t];

    for (int k = 0; k < 12; ++k) {
        // stage Wp(k) into wpf2[k&1] (pure ds_write from regs)
        f16x8* wps = (f16x8*)(smem + 40960 + (k & 1) * 6144);
        wps[t] = nw0;
        if (t < 128) wps[256 + t] = nw1;

        // issue next chunk's x loads (consumed next iteration)
        if (k < 11) {
            int cn = (k + 1) * 8 + wv * 2;
            LOADCH(nxt, 0, cn)
            LOADCH(nxt, 1, cn + 1)
        }

        // overlap: MFMA of previous chunk (different LDS buffers)
        if (k > 0) DO_MFMA(k - 1)

        // prefetch next chunk's Wp
        if (k < 11) {
            int cb = (k + 1) * 384;
            nw0 = wpf_g[cb + t];
            if (t < 128) nw1 = wpf_g[cb + 256 + t];
        }

        // compute u(k): this wave's 2 channels, 4 cols each
        int cu0 = k * 8 + wv * 2;
        f16x4 uv[2][4];
        #pragma unroll
        for (int q = 0; q < 2; ++q) {
            int cu = cu0 + q;
            int c1a = cu * 2;
            float wa0 = w1f[c1a*3+0], wa1 = w1f[c1a*3+1], wa2 = w1f[c1a*3+2], ba = b1f[c1a];
            float wb0 = w1f[c1a*3+3], wb1 = w1f[c1a*3+4], wb2 = w1f[c1a*3+5], bb = b1f[c1a+1];

            float va[4], vb[4];
            #pragma unroll
            for (int j = 0; j < 4; ++j) {
                float tt = ymok ? cur.T[q][j] : 0.f;
                float bt = ypok ? cur.B[q][j] : 0.f;
                va[j] = fmaf(wa0, tt, fmaf(wa1, cur.M[q][j], fmaf(wa2, bt, ba)));
                vb[j] = fmaf(wb0, tt, fmaf(wb1, cur.M[q][j], fmaf(wb2, bt, bb)));
            }
            // edge column (lazy; conv2 zero-pads BN1 output outside image)
            float vea = 0.f, veb = 0.f;
            if (ev) {
                const float* e_ = xw + (long)cu * HW + secol;
                float eM = e_[0];
                float eT = ymok ? e_[tm] : 0.f;
                float eB = ypok ? e_[tp] : 0.f;
                vea = fmaf(wa0, eT, fmaf(wa1, eM, fmaf(wa2, eB, ba)));
                veb = fmaf(wb0, eT, fmaf(wb1, eM, fmaf(wb2, eB, bb)));
            }

            float vLa = __shfl(va[3], (lane + 63) & 63);
            float vLb = __shfl(vb[3], (lane + 63) & 63);
            float vRa = __shfl(va[0], (lane + 1) & 63);
            float vRb = __shfl(vb[0], (lane + 1) & 63);
            if (c4 == 0)  { vLa = vea; vLb = veb; }
            if (c4 == 15) { vRa = vea; vRb = veb; }

            int c2b = cu * 4;
            float pa[6] = {vLa, va[0], va[1], va[2], va[3], vRa};
            float pb[6] = {vLb, vb[0], vb[1], vb[2], vb[3], vRb};
            #pragma unroll
            for (int j = 0; j < 4; ++j) {
                #pragma unroll
                for (int jj = 0; jj < 4; ++jj) {
                    float p0 = (jj < 2) ? pa[j]     : pb[j];
                    float p1 = (jj < 2) ? pa[j + 1] : pb[j + 1];
                    float p2 = (jj < 2) ? pa[j + 2] : pb[j + 2];
                    float tv = fmaf(w2f[(c2b+jj)*3+0], p0,
                               fmaf(w2f[(c2b+jj)*3+1], p1,
                               fmaf(w2f[(c2b+jj)*3+2], p2, b2f[c2b+jj])));
                    uv[q][j][jj] = (_Float16)fminf(fmaxf(tv, 0.f), 6.f);
                }
            }
        }
        {
            char* ub0 = smem + (k & 1) * 20480 + (r * 64 + 4 * c4) * 80 + slot * 16;
            #pragma unroll
            for (int j = 0; j < 4; ++j) {
                f16x8 w = __builtin_shufflevector(uv[0][j], uv[1][j], 0, 1, 2, 3, 4, 5, 6, 7);
                *(f16x8*)(ub0 + j * 80) = w;
            }
        }
        cur = nxt;
        __syncthreads();   // u(k)+wpf(k) visible; MFMA(k-1) reads complete
    }
    DO_MFMA(11)
    __syncthreads();   // all MFMA LDS reads done before aliasing smem with h

    // ---- epilogue: bn3 -> h_s[96][264] (f16) -> coalesced stores + sums -------
    _Float16* h_s = (_Float16*)smem;   // 50688 B <= 53248
    const float* s3  = ws + WS_S3;
    const float* b3f = ws + WS_B3;
    #pragma unroll
    for (int rt = 0; rt < 6; ++rt) {
        #pragma unroll
        for (int ct = 0; ct < 4; ++ct) {
            int p = wv * 64 + ct * 16 + col16;
            #pragma unroll
            for (int rr = 0; rr < 4; ++rr) {
                int m = rt * 16 + g * 4 + rr;
                h_s[m * 264 + p] = (_Float16)fmaf(acc[rt][ct][rr], s3[m], b3f[m]);
            }
        }
    }
    __syncthreads();

    #pragma unroll
    for (int i = 0; i < 12; ++i) {
        int flat = i * 2048 + t * 8;           // covers 96*256 exactly
        int m = flat >> 8;
        int p = flat & 255;
        f16x8 hv = *(const f16x8*)(h_s + m * 264 + p);
        int row = y0 + (p >> 6);
        int colg = x0 + (p & 63);
        *(f16x8*)(h_out + ((long)(b * CINC + m)) * HW + (long)row * WID + colg) = hv;

        float s = 0.f;
        if (!(x0 == 48 && (p & 63) < 16)) {    // overlap cols 48..63 counted by half-0
            #pragma unroll
            for (int e = 0; e < 8; ++e) s += (float)hv[e];
        }
        s += __shfl_xor(s, 1);
        s += __shfl_xor(s, 2);
        s += __shfl_xor(s, 4);
        s += __shfl_xor(s, 8);
        s += __shfl_xor(s, 16);
        if ((lane & 31) == 0) atomicAdd(&ssum[m], s);
    }
    __syncthreads();
    if (t < CINC) atomicAdd(&sums[b * CINC + t], ssum[t]);
}

// ---------------- gates: mean(h) -> fc1+relu -> fc2 -> hardsig -> a1,b1 -------
__global__ __launch_bounds__(192) void k_gates(const float* __restrict__ sums,
                                               const float* __restrict__ fc1w,
                                               const float* __restrict__ fc1b,
                                               const float* __restrict__ fc2w,
                                               const float* __restrict__ fc2b,
                                               float* __restrict__ a1b1)
{
    __shared__ float mean_s[CINC];
    __shared__ float mid[24];
    int b = blockIdx.x;
    int t = threadIdx.x;     // 192

    if (t < CINC) mean_s[t] = sums[b * CINC + t] * (1.0f / 12544.0f);
    __syncthreads();
    if (t < 24) {
        float d = fc1b[t];
        #pragma unroll 4
        for (int c = 0; c < CINC; ++c) d = fmaf(fc1w[t * CINC + c], mean_s[c], d);
        mid[t] = fmaxf(d, 0.f);
    }
    __syncthreads();
    {
        float d = fc2b[t];
        #pragma unroll
        for (int j = 0; j < 24; ++j) d = fmaf(fc2w[t * 24 + j], mid[j], d);
        float y = fminf(fmaxf(d + 3.f, 0.f), 6.f) * (1.f / 6.f);
        y = (y - 0.5f) * 4.f;
        a1b1[b * 192 + t] = (t < CINC) ? (y + 1.f) : y;
    }
}

// ---------------- final: h*a1 + roll(h)*b1, shuffle(48), + x (pure streaming) --
__global__ __launch_bounds__(256) void k_final(const _Float16* __restrict__ h,
                                               const float* __restrict__ xin,
                                               const float* __restrict__ a1b1,
                                               float* __restrict__ out)
{
    int q = blockIdx.x * 256 + threadIdx.x;      // 4,816,896 quads total (exact)
    int pos4 = q % 3136;
    int bo = q / 3136;
    int o = bo % CINC, b = bo / CINC;
    int c = (o % 48) * 2 + (o / 48);             // shuffle(48) folded
    int cn = (c + 1) % CINC;                      // channel roll

    float av = a1b1[b * 192 + c];
    float bv = a1b1[b * 192 + 96 + c];

    long hb = (long)b * CINC * HW;
    f16x4 hv4 = *(const f16x4*)(h + hb + (long)c  * HW + pos4 * 4);
    f16x4 h2v = *(const f16x4*)(h + hb + (long)cn * HW + pos4 * 4);

    long xo = ((long)(b * CINC + o)) * HW + pos4 * 4;
    f32x4 xv = *(const f32x4*)(xin + xo);
    f32x4 rr;
    #pragma unroll
    for (int j = 0; j < 4; ++j)
        rr[j] = fmaf((float)hv4[j], av, fmaf((float)h2v[j], bv, xv[j]));
    *(f32x4*)(out + xo) = rr;
}

extern "C" void kernel_launch(void* const* d_in, const int* in_sizes, int n_in,
                              void* d_out, int out_size, void* d_ws, size_t ws_size,
                              hipStream_t stream)
{
    const float* x    = (const float*)d_in[0];
    const float* wdw1 = (const float*)d_in[1];
    const float* g1   = (const float*)d_in[2];
    const float* b1   = (const float*)d_in[3];
    const float* m1   = (const float*)d_in[4];
    const float* v1   = (const float*)d_in[5];
    const float* wdw2 = (const float*)d_in[6];
    const float* g2   = (const float*)d_in[7];
    const float* b2   = (const float*)d_in[8];
    const float* m2   = (const float*)d_in[9];
    const float* v2   = (const float*)d_in[10];
    const float* wpw  = (const float*)d_in[11];
    const float* g3   = (const float*)d_in[12];
    const float* b3   = (const float*)d_in[13];
    const float* m3   = (const float*)d_in[14];
    const float* v3   = (const float*)d_in[15];
    const float* fc1w = (const float*)d_in[16];
    const float* fc1b = (const float*)d_in[17];
    const float* fc2w = (const float*)d_in[18];
    const float* fc2b = (const float*)d_in[19];

    float* ws   = (float*)d_ws;
    float* sums = ws + WS_S;
    float* a1b1 = ws + WS_A1B1;
    _Float16* hbuf = (_Float16*)((char*)d_ws + WS_H_BYTES);
    float* out  = (float*)d_out;

    hipMemsetAsync(sums, 0, 1536 * sizeof(float), stream);
    k_prep<<<dim3(40), dim3(256), 0, stream>>>(
        wdw1, g1, b1, m1, v1, wdw2, g2, b2, m2, v2,
        wpw, g3, b3, m3, v3, ws);
    k_main11<<<dim3(896), dim3(256), 0, stream>>>(x, ws, sums, hbuf);
    k_gates<<<dim3(BATCH), dim3(192), 0, stream>>>(sums, fc1w, fc1b, fc2w, fc2b, a1b1);
    k_final<<<dim3(4816896 / 256), dim3(256), 0, stream>>>(hbuf, x, a1b1, out);
}

// Round 19
// 119.408 us; speedup vs baseline: 3.2751x; 1.3783x over previous
//
#include <hip/hip_runtime.h>
#include <hip/hip_bf16.h>

#define BATCH 16
#define CINC 96
#define HGT 112
#define WID 112
#define HW 12544          // 112*112
#define C1N 192
#define C2N 384
#define EPSV 1e-5f

typedef _Float16 f16x8 __attribute__((ext_vector_type(8)));
typedef _Float16 f16x4 __attribute__((ext_vector_type(4)));
typedef float    f32x4 __attribute__((ext_vector_type(4)));

// d_ws layout (float offsets unless noted)
#define WS_S      0        // 16*96 f32 h-sums (zeroed each launch)
#define WS_A1B1   1536     // 16*192 f32
#define WS_W1F    4608     // 192*3
#define WS_B1F    5184     // 192
#define WS_W2F    5376     // 384*3
#define WS_B2F    6528     // 384
#define WS_S3     6912     // 96
#define WS_B3     7008     // 96
#define WS_WPF_BYTES (7104*4)                    // f16 wpf[chunk][ks][rt][lane][8]
#define WS_H_BYTES   (WS_WPF_BYTES + CINC*C2N*2) // f16 h[16][96][12544] = 38.5 MB

// ---------------- prep: fold BN into weights; Wp -> chunk-contiguous fragments --
// wpf[(((ksg)*6+rt)*64+lane)*8+e] = Wp[rt*16+(lane&15)][ksg*32+(lane>>4)*8+e]
// Wp[m][k] = w_pw[m][(k%64)*6 + k/64]  (channel shuffle groups=6 folded)
__global__ void k_prep(const float* __restrict__ wdw1, const float* __restrict__ g1,
                       const float* __restrict__ bb1, const float* __restrict__ m1,
                       const float* __restrict__ v1,
                       const float* __restrict__ wdw2, const float* __restrict__ g2,
                       const float* __restrict__ bb2, const float* __restrict__ m2,
                       const float* __restrict__ v2,
                       const float* __restrict__ wpw, const float* __restrict__ g3,
                       const float* __restrict__ bb3, const float* __restrict__ m3,
                       const float* __restrict__ v3,
                       float* ws)
{
    int t = blockIdx.x * blockDim.x + threadIdx.x;
    int stride = gridDim.x * blockDim.x;
    float* w1f = ws + WS_W1F; float* b1f = ws + WS_B1F;
    float* w2f = ws + WS_W2F; float* b2f = ws + WS_B2F;
    float* s3  = ws + WS_S3;  float* b3f = ws + WS_B3;
    _Float16* wpf = (_Float16*)((char*)ws + WS_WPF_BYTES);

    for (int c = t; c < C1N; c += stride) {
        float s = g1[c] / sqrtf(v1[c] + EPSV);
        w1f[c*3+0] = wdw1[c*3+0] * s;
        w1f[c*3+1] = wdw1[c*3+1] * s;
        w1f[c*3+2] = wdw1[c*3+2] * s;
        b1f[c] = bb1[c] - m1[c] * s;
    }
    for (int c = t; c < C2N; c += stride) {
        float s = g2[c] / sqrtf(v2[c] + EPSV);
        w2f[c*3+0] = wdw2[c*3+0] * s;
        w2f[c*3+1] = wdw2[c*3+1] * s;
        w2f[c*3+2] = wdw2[c*3+2] * s;
        b2f[c] = bb2[c] - m2[c] * s;
    }
    for (int c = t; c < CINC; c += stride) {
        float s = g3[c] / sqrtf(v3[c] + EPSV);
        s3[c] = s; b3f[c] = bb3[c] - m3[c] * s;
    }
    for (int idx = t; idx < CINC * C2N; idx += stride) {
        int e = idx & 7;
        int l2 = idx >> 3;
        int lane = l2 & 63;
        int l3 = l2 >> 6;
        int rt = l3 % 6, ksg = l3 / 6;
        int m = rt * 16 + (lane & 15);
        int k = ksg * 32 + (lane >> 4) * 8 + e;
        int o = (k & 63) * 6 + (k >> 6);
        wpf[idx] = (_Float16)wpw[m * C2N + o];
    }
}

// x-data for one channel pair
struct PairX {
    f32x4 T[2], M[2], B[2];
    float eT[2], eM[2], eB[2];
};

// ---------------- main: preload-pipelined dw -> LDS Wp MFMA -> h+sums ----------
// block = 4 rows x 64 cols; thread = (row r, 4-col c4); 72 KB LDS -> 2 blk/CU
__global__ __launch_bounds__(256, 2) void k_main8(const float* __restrict__ x,
                                                  const float* __restrict__ ws,
                                                  float* __restrict__ sums,
                                                  _Float16* __restrict__ h_out)
{
    __shared__ __align__(16) char u_raw[256 * 208];   // u tile (slot-rotated); h_s aliases
    __shared__ __align__(16) f16x8 wpf_s[1152];       // Wp chunk fragments (18432 B)
    __shared__ float ssum[CINC];

    int t   = threadIdx.x;
    int bid = blockIdx.x;
    int logical = (bid & 7) * 112 + (bid >> 3);       // XCD-chunked (896 = 8*112)
    int b   = logical / 56;
    int rem = logical - b * 56;
    int y0  = (rem >> 1) * 4;
    int x0  = (rem & 1) * 48;

    int wv = t >> 6, lane = t & 63;
    int r = lane >> 4, c4 = lane & 15;
    int gy = y0 + r;
    int gc = x0 + 4 * c4;
    int col16 = c4, g = r;                            // MFMA-phase aliases

    const float* w1f = ws + WS_W1F; const float* b1f = ws + WS_B1F;
    const float* w2f = ws + WS_W2F; const float* b2f = ws + WS_B2F;

    if (t < CINC) ssum[t] = 0.f;

    bool ymok = gy >= 1;
    bool ypok = gy + 1 < HGT;
    bool isE  = (c4 == 0) | (c4 == 15);
    int  ecol = (c4 == 0) ? (x0 - 1) : (x0 + 64);
    bool ev   = isE && ((unsigned)ecol < (unsigned)WID);
    int  secol = ev ? ecol : 0;
    int  tm = ymok ? -WID : 0;
    int  tp = ypok ?  WID : 0;

    f32x4 acc[6][4];
    #pragma unroll
    for (int rt = 0; rt < 6; ++rt)
        #pragma unroll
        for (int ct = 0; ct < 4; ++ct) acc[rt][ct] = (f32x4){0.f, 0.f, 0.f, 0.f};

    const f16x8* wpf_g = (const f16x8*)((const char*)ws + WS_WPF_BYTES);
    long xb = (long)b * CINC * HW;
    const float* xw = x + xb + (long)gy * WID;        // + cu*HW + col

    int rotbase = 3 * r + c4;
    char* ub0 = u_raw + (r * 64 + 4 * c4) * 208;

    // prefetch chunk 0's Wp fragments into registers
    f16x8 nw0 = wpf_g[t];
    f16x8 nw1 = wpf_g[256 + t];
    f16x8 nw2 = wpf_g[512 + t];
    f16x8 nw3 = wpf_g[768 + t];
    f16x8 nw4 = nw0;
    if (t < 128) nw4 = wpf_g[1024 + t];

    #define LOADCH(dst, q, cuq) {                                         \
        const float* p_ = xw + (long)(cuq) * HW;                          \
        (dst).M[q] = *(const f32x4*)(p_ + gc);                            \
        (dst).T[q] = *(const f32x4*)(p_ + gc + tm);                       \
        (dst).B[q] = *(const f32x4*)(p_ + gc + tp);                       \
        if (isE) {                                                        \
            const float* e_ = p_ + secol;                                 \
            (dst).eM[q] = e_[0]; (dst).eT[q] = e_[tm]; (dst).eB[q] = e_[tp]; \
        } }

    for (int chunk = 0; chunk < 4; ++chunk) {
        if (chunk) __syncthreads();       // prev MFMA reads done before overwrite

        // stage Wp fragments from prefetch regs (pure ds_write, no global wait)
        wpf_s[t] = nw0;
        wpf_s[256 + t] = nw1;
        wpf_s[512 + t] = nw2;
        wpf_s[768 + t] = nw3;
        if (t < 128) wpf_s[1024 + t] = nw4;

        int cbase = chunk * 24 + wv * 6;
        PairX A, B;
        LOADCH(A, 0, cbase + 0)
        LOADCH(A, 1, cbase + 1)

        // 3 pairs, software-pipelined: load pair p+1 while computing pair p
        #pragma unroll
        for (int p = 0; p < 3; ++p) {
            if (p == 0) { LOADCH(B, 0, cbase + 2) LOADCH(B, 1, cbase + 3) }
            if (p == 1) { LOADCH(A, 0, cbase + 4) LOADCH(A, 1, cbase + 5) }
            PairX& C = (p == 1) ? B : A;

            f16x4 uv[2][4];
            #pragma unroll
            for (int q = 0; q < 2; ++q) {
                int cu = cbase + 2 * p + q;
                int c1a = cu * 2;
                float wa0 = w1f[c1a*3+0], wa1 = w1f[c1a*3+1], wa2 = w1f[c1a*3+2], ba = b1f[c1a];
                float wb0 = w1f[c1a*3+3], wb1 = w1f[c1a*3+4], wb2 = w1f[c1a*3+5], bb = b1f[c1a+1];

                float va[4], vb[4];
                #pragma unroll
                for (int j = 0; j < 4; ++j) {
                    float tt = ymok ? C.T[q][j] : 0.f;
                    float bt = ypok ? C.B[q][j] : 0.f;
                    va[j] = fmaf(wa0, tt, fmaf(wa1, C.M[q][j], fmaf(wa2, bt, ba)));
                    vb[j] = fmaf(wb0, tt, fmaf(wb1, C.M[q][j], fmaf(wb2, bt, bb)));
                }
                // conv2 zero-pads BN1 output: out-of-image edge column -> 0
                float etS = (ymok && ev) ? C.eT[q] : 0.f;
                float ebS = (ypok && ev) ? C.eB[q] : 0.f;
                float emS = ev ? C.eM[q] : 0.f;
                float vea = ev ? fmaf(wa0, etS, fmaf(wa1, emS, fmaf(wa2, ebS, ba))) : 0.f;
                float veb = ev ? fmaf(wb0, etS, fmaf(wb1, emS, fmaf(wb2, ebS, bb))) : 0.f;

                float vLa = __shfl(va[3], (lane + 63) & 63);
                float vLb = __shfl(vb[3], (lane + 63) & 63);
                float vRa = __shfl(va[0], (lane + 1) & 63);
                float vRb = __shfl(vb[0], (lane + 1) & 63);
                if (c4 == 0)  { vLa = vea; vLb = veb; }
                if (c4 == 15) { vRa = vea; vRb = veb; }

                int c2b = cu * 4;
                float pa[6] = {vLa, va[0], va[1], va[2], va[3], vRa};
                float pb[6] = {vLb, vb[0], vb[1], vb[2], vb[3], vRb};
                #pragma unroll
                for (int j = 0; j < 4; ++j) {
                    #pragma unroll
                    for (int jj = 0; jj < 4; ++jj) {
                        float p0 = (jj < 2) ? pa[j]     : pb[j];
                        float p1 = (jj < 2) ? pa[j + 1] : pb[j + 1];
                        float p2 = (jj < 2) ? pa[j + 2] : pb[j + 2];
                        float tv = fmaf(w2f[(c2b+jj)*3+0], p0,
                                   fmaf(w2f[(c2b+jj)*3+1], p1,
                                   fmaf(w2f[(c2b+jj)*3+2], p2, b2f[c2b+jj])));
                        uv[q][j][jj] = (_Float16)fminf(fmaxf(tv, 0.f), 6.f);
                    }
                }
            }
            // paired 16-B store: k-cell = wv*3+p, rotated
            int slot = (wv * 3 + p + rotbase) % 12;
            char* ubase = ub0 + slot * 16;
            #pragma unroll
            for (int j = 0; j < 4; ++j) {
                f16x8 w = __builtin_shufflevector(uv[0][j], uv[1][j], 0, 1, 2, 3, 4, 5, 6, 7);
                *(f16x8*)(ubase + j * 208) = w;
            }
        }

        // prefetch next chunk's Wp during barrier + MFMA
        if (chunk < 3) {
            int cb = (chunk + 1) * 1152;
            nw0 = wpf_g[cb + t];
            nw1 = wpf_g[cb + 256 + t];
            nw2 = wpf_g[cb + 512 + t];
            nw3 = wpf_g[cb + 768 + t];
            if (t < 128) nw4 = wpf_g[cb + 1024 + t];
        }
        __syncthreads();   // u + wpf_s ready

        // MFMA: acc += Wp[:, chunk slice] * u  (all operands in LDS)
        __builtin_amdgcn_s_setprio(1);
        #pragma unroll
        for (int ks = 0; ks < 3; ++ks) {
            f16x8 bfr[4];
            #pragma unroll
            for (int ct = 0; ct < 4; ++ct) {
                int pos = wv * 64 + ct * 16 + col16;
                int sl = (ks * 4 + g + 3 * wv + ((pos >> 2) & 15)) % 12;
                bfr[ct] = *(const f16x8*)(u_raw + pos * 208 + sl * 16);
            }
            #pragma unroll
            for (int rt = 0; rt < 6; ++rt) {
                f16x8 afr = wpf_s[(ks * 6 + rt) * 64 + lane];
                #pragma unroll
                for (int ct = 0; ct < 4; ++ct)
                    acc[rt][ct] = __builtin_amdgcn_mfma_f32_16x16x32_f16(afr, bfr[ct], acc[rt][ct], 0, 0, 0);
            }
        }
        __builtin_amdgcn_s_setprio(0);
    }
    __syncthreads();   // last MFMA reads done before aliasing u_raw with h

    // stage h (bn3, f16) into LDS: h_s[m][264]
    _Float16* h_s = (_Float16*)u_raw;
    const float* s3  = ws + WS_S3;
    const float* b3f = ws + WS_B3;
    #pragma unroll
    for (int rt = 0; rt < 6; ++rt) {
        #pragma unroll
        for (int ct = 0; ct < 4; ++ct) {
            int p = wv * 64 + ct * 16 + col16;
            #pragma unroll
            for (int rr = 0; rr < 4; ++rr) {
                int m = rt * 16 + g * 4 + rr;
                h_s[m * 264 + p] = (_Float16)fmaf(acc[rt][ct][rr], s3[m], b3f[m]);
            }
        }
    }
    __syncthreads();

    // coalesced full-line h stores + channel sums (overlap cols masked)
    #pragma unroll
    for (int i = 0; i < 12; ++i) {
        int flat = i * 2048 + t * 8;           // covers 96*256 exactly
        int m = flat >> 8;
        int p = flat & 255;
        f16x8 hv = *(const f16x8*)(h_s + m * 264 + p);
        int row = y0 + (p >> 6);
        int colg = x0 + (p & 63);
        *(f16x8*)(h_out + ((long)(b * CINC + m)) * HW + (long)row * WID + colg) = hv;

        float s = 0.f;
        if (!(x0 == 48 && (p & 63) < 16)) {    // overlap cols 48..63 counted by half-0
            #pragma unroll
            for (int e = 0; e < 8; ++e) s += (float)hv[e];
        }
        s += __shfl_xor(s, 1);
        s += __shfl_xor(s, 2);
        s += __shfl_xor(s, 4);
        s += __shfl_xor(s, 8);
        s += __shfl_xor(s, 16);
        if ((lane & 31) == 0) atomicAdd(&ssum[m], s);
    }
    __syncthreads();
    if (t < CINC) atomicAdd(&sums[b * CINC + t], ssum[t]);
}

// ---------------- gates: mean(h) -> fc1+relu -> fc2 -> hardsig -> a1,b1 -------
__global__ __launch_bounds__(192) void k_gates(const float* __restrict__ sums,
                                               const float* __restrict__ fc1w,
                                               const float* __restrict__ fc1b,
                                               const float* __restrict__ fc2w,
                                               const float* __restrict__ fc2b,
                                               float* __restrict__ a1b1)
{
    __shared__ float mean_s[CINC];
    __shared__ float mid[24];
    int b = blockIdx.x;
    int t = threadIdx.x;     // 192

    if (t < CINC) mean_s[t] = sums[b * CINC + t] * (1.0f / 12544.0f);
    __syncthreads();
    if (t < 24) {
        float d = fc1b[t];
        #pragma unroll 4
        for (int c = 0; c < CINC; ++c) d = fmaf(fc1w[t * CINC + c], mean_s[c], d);
        mid[t] = fmaxf(d, 0.f);
    }
    __syncthreads();
    {
        float d = fc2b[t];
        #pragma unroll
        for (int j = 0; j < 24; ++j) d = fmaf(fc2w[t * 24 + j], mid[j], d);
        float y = fminf(fmaxf(d + 3.f, 0.f), 6.f) * (1.f / 6.f);
        y = (y - 0.5f) * 4.f;
        a1b1[b * 192 + t] = (t < CINC) ? (y + 1.f) : y;
    }
}

// ---------------- final: h*a1 + roll(h)*b1, shuffle(48), + x (pure streaming) --
__global__ __launch_bounds__(256) void k_final(const _Float16* __restrict__ h,
                                               const float* __restrict__ xin,
                                               const float* __restrict__ a1b1,
                                               float* __restrict__ out)
{
    int q = blockIdx.x * 256 + threadIdx.x;      // 4,816,896 quads total (exact)
    int pos4 = q % 3136;
    int bo = q / 3136;
    int o = bo % CINC, b = bo / CINC;
    int c = (o % 48) * 2 + (o / 48);             // shuffle(48) folded
    int cn = (c + 1) % CINC;                      // channel roll

    float av = a1b1[b * 192 + c];
    float bv = a1b1[b * 192 + 96 + c];

    long hb = (long)b * CINC * HW;
    f16x4 hv4 = *(const f16x4*)(h + hb + (long)c  * HW + pos4 * 4);
    f16x4 h2v = *(const f16x4*)(h + hb + (long)cn * HW + pos4 * 4);

    long xo = ((long)(b * CINC + o)) * HW + pos4 * 4;
    f32x4 xv = *(const f32x4*)(xin + xo);
    f32x4 rr;
    #pragma unroll
    for (int j = 0; j < 4; ++j)
        rr[j] = fmaf((float)hv4[j], av, fmaf((float)h2v[j], bv, xv[j]));
    *(f32x4*)(out + xo) = rr;
}

extern "C" void kernel_launch(void* const* d_in, const int* in_sizes, int n_in,
                              void* d_out, int out_size, void* d_ws, size_t ws_size,
                              hipStream_t stream)
{
    const float* x    = (const float*)d_in[0];
    const float* wdw1 = (const float*)d_in[1];
    const float* g1   = (const float*)d_in[2];
    const float* b1   = (const float*)d_in[3];
    const float* m1   = (const float*)d_in[4];
    const float* v1   = (const float*)d_in[5];
    const float* wdw2 = (const float*)d_in[6];
    const float* g2   = (const float*)d_in[7];
    const float* b2   = (const float*)d_in[8];
    const float* m2   = (const float*)d_in[9];
    const float* v2   = (const float*)d_in[10];
    const float* wpw  = (const float*)d_in[11];
    const float* g3   = (const float*)d_in[12];
    const float* b3   = (const float*)d_in[13];
    const float* m3   = (const float*)d_in[14];
    const float* v3   = (const float*)d_in[15];
    const float* fc1w = (const float*)d_in[16];
    const float* fc1b = (const float*)d_in[17];
    const float* fc2w = (const float*)d_in[18];
    const float* fc2b = (const float*)d_in[19];

    float* ws   = (float*)d_ws;
    float* sums = ws + WS_S;
    float* a1b1 = ws + WS_A1B1;
    _Float16* hbuf = (_Float16*)((char*)d_ws + WS_H_BYTES);
    float* out  = (float*)d_out;

    hipMemsetAsync(sums, 0, 1536 * sizeof(float), stream);
    k_prep<<<dim3(40), dim3(256), 0, stream>>>(
        wdw1, g1, b1, m1, v1, wdw2, g2, b2, m2, v2,
        wpw, g3, b3, m3, v3, ws);
    k_main8<<<dim3(896), dim3(256), 0, stream>>>(x, ws, sums, hbuf);
    k_gates<<<dim3(BATCH), dim3(192), 0, stream>>>(sums, fc1w, fc1b, fc2w, fc2b, a1b1);
    k_final<<<dim3(4816896 / 256), dim3(256), 0, stream>>>(hbuf, x, a1b1, out);
}